// Round 13
// baseline (1859.163 us; speedup 1.0000x reference)
//
#include <hip/hip_runtime.h>
#include <hip/hip_bf16.h>

#define N_NODES 10000
#define E_EDGES 160000
#define ETOT    170000   // E + N self loops
#define H_HEADS 8
#define C_CH    128
#define D_DIM   1024
#define NBLK    3
#define NGRAPH  64
#define NEG_SLOPE 0.2f
#define BN_EPS  1e-5f

typedef __attribute__((ext_vector_type(8))) _Float16 half8;
typedef __attribute__((ext_vector_type(4))) _Float16 half4;
typedef __attribute__((ext_vector_type(2))) _Float16 half2v;
typedef __attribute__((ext_vector_type(4))) float f32x4;

// first index i in sorted batch[0..N) with batch[i] >= g
__device__ inline int lower_bound_batch(const int* __restrict__ batch, int g) {
    int lo = 0, hi = N_NODES;
    while (lo < hi) {
        int mid = (lo + hi) >> 1;
        if (batch[mid] < g) lo = mid + 1;
        else hi = mid;
    }
    return lo;
}

// ---------------- CSR build ----------------
__global__ void deg_kernel(const int* __restrict__ ei, int* __restrict__ deg) {
    int tid = blockIdx.x * blockDim.x + threadIdx.x;
    if (tid >= ETOT) return;
    int dst = (tid < E_EDGES) ? ei[E_EDGES + tid] : (tid - E_EDGES);
    atomicAdd(&deg[dst], 1);
}

__global__ void scan_kernel(const int* __restrict__ deg, int* __restrict__ ioff) {
    __shared__ int part[256];
    int t = threadIdx.x;
    const int CH = (N_NODES + 255) / 256; // 40
    int base = t * CH;
    int s = 0;
    for (int j = 0; j < CH; ++j) {
        int idx = base + j;
        if (idx < N_NODES) s += deg[idx];
    }
    part[t] = s;
    __syncthreads();
    for (int o = 1; o < 256; o <<= 1) {
        int v = 0;
        if (t >= o) v = part[t - o];
        __syncthreads();
        part[t] += v;
        __syncthreads();
    }
    int run = (t == 0) ? 0 : part[t - 1];
    for (int j = 0; j < CH; ++j) {
        int idx = base + j;
        if (idx < N_NODES) { ioff[idx] = run; run += deg[idx]; }
    }
}

__global__ void scatter_kernel(const int* __restrict__ ei, int* __restrict__ ioff,
                               int* __restrict__ csr_src) {
    int tid = blockIdx.x * blockDim.x + threadIdx.x;
    if (tid >= ETOT) return;
    int src, dst;
    if (tid < E_EDGES) { src = ei[tid]; dst = ei[E_EDGES + tid]; }
    else { src = dst = tid - E_EDGES; }
    int pos = atomicAdd(&ioff[dst], 1);
    csr_src[pos] = src;
}

// ---------------- x -> fp16 ----------------
__global__ __launch_bounds__(256) void xconv_kernel(const float* __restrict__ in,
                                                    _Float16* __restrict__ o, int n4) {
    int i = blockIdx.x * blockDim.x + threadIdx.x;
    if (i >= n4) return;
    float4 v = ((const float4*)in)[i];
    half4 h = {(_Float16)v.x, (_Float16)v.y, (_Float16)v.z, (_Float16)v.w};
    ((half4*)o)[i] = h;
}

// W [k][n] fp32 -> Wt [n][k] fp16 (transposed); blockIdx.z = layer
__global__ __launch_bounds__(256) void wtconv_kernel(const float* __restrict__ Wall,
                                                     _Float16* __restrict__ t16all) {
    const float* W = Wall + (size_t)blockIdx.z * D_DIM * D_DIM;
    _Float16* t16 = t16all + (size_t)blockIdx.z * D_DIM * D_DIM;
    __shared__ float t[32][33];
    int bn = blockIdx.x * 32;
    int bk = blockIdx.y * 32;
    int tx = threadIdx.x & 31;
    int ty = threadIdx.x >> 5;
#pragma unroll
    for (int r = 0; r < 32; r += 8)
        t[ty + r][tx] = W[(size_t)(bk + ty + r) * D_DIM + bn + tx];
    __syncthreads();
#pragma unroll
    for (int r = 0; r < 32; r += 8)
        t16[(size_t)(bn + ty + r) * D_DIM + bk + tx] = (_Float16)t[tx][ty + r];
}

// ---------------- fp16 MFMA GEMM + fused attention-logit epilogue ----------------
// R8 tile config (128x128, 4 waves) with XCD-flipped block mapping: 1D grid 640,
// c = bx&7 (= XCD under the %8 round-robin heuristic, validated R7), head =
// (bx>>3)&7, mt = c + 8*(bx>>6). Each XCD owns m-tiles {c, c+8, ...}: one hot
// 256 KB A-tile (reused by 8 consecutive head-blocks) + 2 MB B per XCD -> L2-
// resident, vs R12's XCD==head mapping where all 8 XCDs streamed the full 20 MB
// A (FETCH 86 MB vs ~25 ideal). Hout layout: head-major [8][N][128].
// Block bx==0 zeroes the bn-stats buffer (consumed by agg, stream-ordered).
__global__ __launch_bounds__(256) void gemm_mfma_kernel(const _Float16* __restrict__ A,
                                                        const _Float16* __restrict__ Bt,
                                                        _Float16* __restrict__ Hout,
                                                        const float* __restrict__ att_s,
                                                        const float* __restrict__ att_d,
                                                        float* __restrict__ asrc,
                                                        float* __restrict__ adst,
                                                        float* __restrict__ stats, int M) {
    __shared__ short As[128 * 32]; // [m][k] fp16 bits
    __shared__ short Bs[128 * 32]; // [n][k]
    __shared__ float sA[128], sD[128];
    int bx = blockIdx.x;
    int tid = threadIdx.x;
    if (bx == 0) {
#pragma unroll
        for (int j = 0; j < 8; ++j) stats[tid + j * 256] = 0.f;
    }
    int c = bx & 7;
    int head = (bx >> 3) & 7;
    int mt = c + 8 * (bx >> 6);
    if (mt >= 79) return;              // only c=7, bx>=576 group tail
    int bm = mt * 128;
    int bn = head * 128;
    int wave = tid >> 6;
    int lane = tid & 63;
    int wm = (wave >> 1) * 64;
    int wn = (wave & 1) * 64;
    int quad = lane >> 4;
    int l16 = lane & 15;

    f32x4 acc[4][4];
#pragma unroll
    for (int i = 0; i < 4; ++i)
#pragma unroll
        for (int j = 0; j < 4; ++j) acc[i][j] = (f32x4){0.f, 0.f, 0.f, 0.f};

    int srow = lane >> 2;
    int scol = (lane & 3) * 16;

    for (int kb = 0; kb < 32; ++kb) {
        int k0 = kb * 32;
#pragma unroll
        for (int r = 0; r < 2; ++r) {
            int arow = wave * 16 + r * 64 + srow;
            int grow = bm + arow;
            if (grow > M - 1) grow = M - 1;
            const char* gp = (const char*)(A + (size_t)grow * 1024 + k0) + scol;
            __builtin_amdgcn_global_load_lds(
                (const __attribute__((address_space(1))) void*)gp,
                (__attribute__((address_space(3))) void*)((char*)As + (wave * 16 + r * 64) * 64),
                16, 0, 0);
        }
#pragma unroll
        for (int r = 0; r < 2; ++r) {
            int brow = wave * 16 + r * 64 + srow;
            const char* gp = (const char*)(Bt + (size_t)(bn + brow) * 1024 + k0) + scol;
            __builtin_amdgcn_global_load_lds(
                (const __attribute__((address_space(1))) void*)gp,
                (__attribute__((address_space(3))) void*)((char*)Bs + (wave * 16 + r * 64) * 64),
                16, 0, 0);
        }
        __syncthreads();

        half8 af[4], bfr[4];
#pragma unroll
        for (int i = 0; i < 4; ++i)
            af[i] = *(const half8*)(As + (wm + i * 16 + l16) * 32 + quad * 8);
#pragma unroll
        for (int j = 0; j < 4; ++j)
            bfr[j] = *(const half8*)(Bs + (wn + j * 16 + l16) * 32 + quad * 8);
#pragma unroll
        for (int i = 0; i < 4; ++i)
#pragma unroll
            for (int j = 0; j < 4; ++j)
                acc[i][j] = __builtin_amdgcn_mfma_f32_16x16x32_f16(af[i], bfr[j], acc[i][j], 0, 0, 0);
        __syncthreads();
    }

    // attention-logit partial dots over this wave's 64 cols
    float wsv[4], wdv[4];
#pragma unroll
    for (int j = 0; j < 4; ++j) {
        int cc = wn + j * 16 + l16;
        wsv[j] = att_s[head * 128 + cc];
        wdv[j] = att_d[head * 128 + cc];
    }
    float psv[4][4], pdv[4][4];
#pragma unroll
    for (int i = 0; i < 4; ++i) {
#pragma unroll
        for (int reg = 0; reg < 4; ++reg) {
            float p = acc[i][0][reg] * wsv[0] + acc[i][1][reg] * wsv[1] +
                      acc[i][2][reg] * wsv[2] + acc[i][3][reg] * wsv[3];
            float q = acc[i][0][reg] * wdv[0] + acc[i][1][reg] * wdv[1] +
                      acc[i][2][reg] * wdv[2] + acc[i][3][reg] * wdv[3];
#pragma unroll
            for (int o = 1; o < 16; o <<= 1) {
                p += __shfl_xor(p, o);
                q += __shfl_xor(q, o);
            }
            psv[i][reg] = p;
            pdv[i][reg] = q;
        }
    }
    if ((wave & 1) == 0 && l16 == 0) {
#pragma unroll
        for (int i = 0; i < 4; ++i)
#pragma unroll
            for (int reg = 0; reg < 4; ++reg) {
                int r = wm + i * 16 + quad * 4 + reg;
                sA[r] = psv[i][reg];
                sD[r] = pdv[i][reg];
            }
    }
    // store h fp16, head-major: Hout[head][row][col128]
#pragma unroll
    for (int i = 0; i < 4; ++i) {
#pragma unroll
        for (int reg = 0; reg < 4; ++reg) {
            int gr = bm + wm + i * 16 + quad * 4 + reg;
            if (gr < M) {
                _Float16* hp = Hout + (size_t)head * N_NODES * 128 + (size_t)gr * 128 + wn + l16;
#pragma unroll
                for (int j = 0; j < 4; ++j) hp[j * 16] = (_Float16)acc[i][j][reg];
            }
        }
    }
    __syncthreads();
    if ((wave & 1) == 1 && l16 == 0) {
#pragma unroll
        for (int i = 0; i < 4; ++i)
#pragma unroll
            for (int reg = 0; reg < 4; ++reg) {
                int r = wm + i * 16 + quad * 4 + reg;
                int gr = bm + r;
                if (gr < M) {
                    asrc[gr * 8 + head] = sA[r] + psv[i][reg];
                    adst[gr * 8 + head] = sD[r] + pdv[i][reg];
                }
            }
    }
}

// ---------------- fused edge-softmax aggregation + barrier-free bn-stats --------
// head = bx&7 (XCD L2 affinity); h16 head-major [8][N][128]; edge loop x4
// unrolled. After the store, each WAVE reduces its two subwarps' fp16-ROUNDED
// y values (lanes l and l+32 share columns -> one shfl_xor(32), no barrier —
// subwarps still retire independently, unlike R11's block-level reduce) and
// atomically adds per-column sum/sumsq to stats. Stats are computed from the
// same rounded y16 that bn_apply reads (R11's self-consistency lesson).
// stats pre-zeroed by gemm block 0 (stream-ordered).
__global__ __launch_bounds__(256) void agg_kernel(const _Float16* __restrict__ h16,
                                                  const float* __restrict__ asrc,
                                                  const float* __restrict__ adst,
                                                  const int* __restrict__ ioff,
                                                  const int* __restrict__ csr_src,
                                                  const _Float16* __restrict__ prevh,
                                                  const float* __restrict__ bias,
                                                  _Float16* __restrict__ yout,
                                                  float* __restrict__ stats) {
    int bx = blockIdx.x;
    int tid = threadIdx.x;
    int head = bx & 7;
    int chunk = bx >> 3;
    int sub = tid >> 5;
    int lane = tid & 31;
    int n = chunk * 8 + sub;          // N=10000 divisible by 8
    int c4 = lane * 4;
    const _Float16* hh = h16 + (size_t)head * N_NODES * 128;
    int start = (n == 0) ? 0 : ioff[n - 1];
    int end = ioff[n];
    float ad = adst[n * 8 + head];
    float den = 0.f;
    float4 acc = make_float4(0.f, 0.f, 0.f, 0.f);
    int p = start;
    for (; p + 4 <= end; p += 4) {
        int s0 = csr_src[p + 0];
        int s1 = csr_src[p + 1];
        int s2 = csr_src[p + 2];
        int s3 = csr_src[p + 3];
        float a0 = asrc[s0 * 8 + head];
        float a1 = asrc[s1 * 8 + head];
        float a2 = asrc[s2 * 8 + head];
        float a3 = asrc[s3 * 8 + head];
        half4 h0 = *(const half4*)(hh + (size_t)s0 * 128 + c4);
        half4 h1 = *(const half4*)(hh + (size_t)s1 * 128 + c4);
        half4 h2 = *(const half4*)(hh + (size_t)s2 * 128 + c4);
        half4 h3 = *(const half4*)(hh + (size_t)s3 * 128 + c4);
        float e0 = a0 + ad; e0 = (e0 > 0.f) ? e0 : NEG_SLOPE * e0;
        float e1 = a1 + ad; e1 = (e1 > 0.f) ? e1 : NEG_SLOPE * e1;
        float e2 = a2 + ad; e2 = (e2 > 0.f) ? e2 : NEG_SLOPE * e2;
        float e3 = a3 + ad; e3 = (e3 > 0.f) ? e3 : NEG_SLOPE * e3;
        float x0 = __expf(e0), x1 = __expf(e1), x2 = __expf(e2), x3 = __expf(e3);
        den += (x0 + x1) + (x2 + x3);
        acc.x += x0 * (float)h0[0] + x1 * (float)h1[0] + x2 * (float)h2[0] + x3 * (float)h3[0];
        acc.y += x0 * (float)h0[1] + x1 * (float)h1[1] + x2 * (float)h2[1] + x3 * (float)h3[1];
        acc.z += x0 * (float)h0[2] + x1 * (float)h1[2] + x2 * (float)h2[2] + x3 * (float)h3[2];
        acc.w += x0 * (float)h0[3] + x1 * (float)h1[3] + x2 * (float)h2[3] + x3 * (float)h3[3];
    }
    for (; p < end; ++p) {
        int s = csr_src[p];
        float e = asrc[s * 8 + head] + ad;
        e = (e > 0.f) ? e : NEG_SLOPE * e;
        float ex = __expf(e);
        den += ex;
        half4 hv = *(const half4*)(hh + (size_t)s * 128 + c4);
        acc.x = fmaf(ex, (float)hv[0], acc.x);
        acc.y = fmaf(ex, (float)hv[1], acc.y);
        acc.z = fmaf(ex, (float)hv[2], acc.z);
        acc.w = fmaf(ex, (float)hv[3], acc.w);
    }
    float invd = 1.0f / den;
    int col = head * 128 + c4;
    half4 ph = *(const half4*)(prevh + (size_t)n * 1024 + col);
    float4 bv = *(const float4*)(bias + col);
    float r0 = fmaf(acc.x, invd, (float)ph[0] + bv.x);
    float r1 = fmaf(acc.y, invd, (float)ph[1] + bv.y);
    float r2 = fmaf(acc.z, invd, (float)ph[2] + bv.z);
    float r3 = fmaf(acc.w, invd, (float)ph[3] + bv.w);
    half4 o = {(_Float16)r0, (_Float16)r1, (_Float16)r2, (_Float16)r3};
    *(half4*)(yout + (size_t)n * 1024 + col) = o;
    // bn-stats from the ROUNDED values (self-consistent with bn_apply's read)
    float q0 = (float)o[0], q1 = (float)o[1], q2 = (float)o[2], q3 = (float)o[3];
    float t0 = q0 * q0, t1 = q1 * q1, t2 = q2 * q2, t3 = q3 * q3;
    q0 += __shfl_xor(q0, 32); t0 += __shfl_xor(t0, 32);
    q1 += __shfl_xor(q1, 32); t1 += __shfl_xor(t1, 32);
    q2 += __shfl_xor(q2, 32); t2 += __shfl_xor(t2, 32);
    q3 += __shfl_xor(q3, 32); t3 += __shfl_xor(t3, 32);
    if ((tid & 63) < 32) {
        atomicAdd(&stats[col + 0], q0); atomicAdd(&stats[1024 + col + 0], t0);
        atomicAdd(&stats[col + 1], q1); atomicAdd(&stats[1024 + col + 1], t1);
        atomicAdd(&stats[col + 2], q2); atomicAdd(&stats[1024 + col + 2], t2);
        atomicAdd(&stats[col + 3], q3); atomicAdd(&stats[1024 + col + 3], t3);
    }
}

// normalize+relu: y16 -> o16 (o is next layer's GEMM A / prev / pool input)
__global__ void bn_apply_kernel(const _Float16* __restrict__ y, const float* __restrict__ stats,
                                const float* __restrict__ gamma, const float* __restrict__ beta,
                                _Float16* __restrict__ oout) {
    int idx4 = blockIdx.x * blockDim.x + threadIdx.x;
    if (idx4 >= N_NODES * D_DIM / 4) return;
    int base = idx4 * 4;
    int col = base & 1023;
    const float invN = 1.0f / (float)N_NODES;
    half4 v = ((const half4*)y)[idx4];
    float r[4];
#pragma unroll
    for (int j = 0; j < 4; ++j) {
        int cc = col + j;
        float mu = stats[cc] * invN;
        float var = stats[1024 + cc] * invN - mu * mu;
        float t = ((float)v[j] - mu) * rsqrtf(var + BN_EPS) * gamma[cc] + beta[cc];
        r[j] = fmaxf(t, 0.f);
    }
    half4 h = {(_Float16)r[0], (_Float16)r[1], (_Float16)r[2], (_Float16)r[3]};
    ((half4*)oout)[idx4] = h;
}

// ---------------- fused pooling + final linear (one dispatch) ----------------
// block g: sum h3 over the graph's row range per column, dot with Wout, reduce.
__global__ __launch_bounds__(256) void poolfinal_kernel(const _Float16* __restrict__ h3,
                                                        const int* __restrict__ batch,
                                                        const float* __restrict__ Wout,
                                                        const float* __restrict__ bout,
                                                        float* __restrict__ out) {
    int g = blockIdx.x;
    int t = threadIdx.x;
    int col = t * 4;
    int lo = lower_bound_batch(batch, g);
    int hi = lower_bound_batch(batch, g + 1);
    float a0 = 0.f, a1 = 0.f, a2 = 0.f, a3 = 0.f;
    for (int r = lo; r < hi; ++r) {
        half4 v = *(const half4*)(h3 + (size_t)r * 1024 + col);
        a0 += (float)v[0]; a1 += (float)v[1]; a2 += (float)v[2]; a3 += (float)v[3];
    }
    float p0 = a0 * Wout[2 * col] + a1 * Wout[2 * (col + 1)] +
               a2 * Wout[2 * (col + 2)] + a3 * Wout[2 * (col + 3)];
    float p1 = a0 * Wout[2 * col + 1] + a1 * Wout[2 * (col + 1) + 1] +
               a2 * Wout[2 * (col + 2) + 1] + a3 * Wout[2 * (col + 3) + 1];
    __shared__ float s0[256], s1[256];
    s0[t] = p0; s1[t] = p1;
    __syncthreads();
    for (int o = 128; o; o >>= 1) {
        if (t < o) { s0[t] += s0[t + o]; s1[t] += s1[t + o]; }
        __syncthreads();
    }
    if (t == 0) {
        float inv = 1.0f / fmaxf((float)(hi - lo), 1.0f);
        out[g * 2 + 0] = s0[0] * inv + bout[0];
        out[g * 2 + 1] = s1[0] * inv + bout[1];
    }
}

extern "C" void kernel_launch(void* const* d_in, const int* in_sizes, int n_in,
                              void* d_out, int out_size, void* d_ws, size_t ws_size,
                              hipStream_t stream) {
    const float* x        = (const float*)d_in[0];
    const int*   ei       = (const int*)d_in[1];
    const int*   batch    = (const int*)d_in[2];
    const float* W        = (const float*)d_in[3];
    const float* att_src  = (const float*)d_in[4];
    const float* att_dst  = (const float*)d_in[5];
    const float* att_bias = (const float*)d_in[6];
    const float* gamma    = (const float*)d_in[7];
    const float* beta     = (const float*)d_in[8];
    const float* Wout     = (const float*)d_in[9];
    const float* bout     = (const float*)d_in[10];
    float* out = (float*)d_out;

    const size_t ND = (size_t)N_NODES * D_DIM;
    float* ws = (float*)d_ws;
    float* asrc   = ws;                                  // N*H
    float* adst   = asrc + (size_t)N_NODES * H_HEADS;    // N*H
    float* stats  = adst + (size_t)N_NODES * H_HEADS;    // 2*D
    int* ideg     = (int*)(stats + 2 * D_DIM);           // N
    int* ioff     = ideg + N_NODES;                      // N
    int* csr_src  = ioff + N_NODES;                      // ETOT
    _Float16* bufP  = (_Float16*)(csr_src + ETOT);       // N*D: x16 -> o1 -> o2
    _Float16* bufO0 = bufP + ND;                         // N*D: o0
    _Float16* h16   = bufO0 + ND;                        // N*D: GEMM out, [8][N][128]
    _Float16* y16   = h16 + ND;                          // N*D: agg out (pre-BN)
    _Float16* Wt3   = y16 + ND;                          // 3*D*D fp16 (W^T)
    // total ≈ 93 MB

    hipMemsetAsync(ideg, 0, N_NODES * sizeof(int), stream);
    deg_kernel<<<(ETOT + 255) / 256, 256, 0, stream>>>(ei, ideg);
    scan_kernel<<<1, 256, 0, stream>>>(ideg, ioff);
    scatter_kernel<<<(ETOT + 255) / 256, 256, 0, stream>>>(ei, ioff, csr_src);
    xconv_kernel<<<(int)(ND / 4 + 255) / 256, 256, 0, stream>>>(x, bufP, (int)(ND / 4));
    wtconv_kernel<<<dim3(32, 32, 3), 256, 0, stream>>>(W, Wt3);

    // layer i: A = Ain[i]; prev = Pin[i] (all fp16); bn output -> Oout[i]
    const _Float16* Ain[3]  = {bufP, bufO0, bufP};
    const _Float16* Pin[3]  = {bufP, bufP, bufO0};
    _Float16* Oout[3]       = {bufO0, bufP, bufP};

    for (int i = 0; i < NBLK; ++i) {
        gemm_mfma_kernel<<<640, 256, 0, stream>>>(
            Ain[i], Wt3 + (size_t)i * D_DIM * D_DIM, h16,
            att_src + i * H_HEADS * C_CH, att_dst + i * H_HEADS * C_CH,
            asrc, adst, stats, N_NODES);
        agg_kernel<<<N_NODES, 256, 0, stream>>>(h16, asrc, adst, ioff, csr_src,
                                                Pin[i], att_bias + i * D_DIM, y16, stats);
        bn_apply_kernel<<<(int)(ND / 4 + 255) / 256, 256, 0, stream>>>(
            y16, stats, gamma + i * D_DIM, beta + i * D_DIM, Oout[i]);
    }

    poolfinal_kernel<<<NGRAPH, 256, 0, stream>>>(bufP, batch, Wout, bout, out);
}

// Round 14
// 608.642 us; speedup vs baseline: 3.0546x; 3.0546x over previous
//
#include <hip/hip_runtime.h>
#include <hip/hip_bf16.h>

#define N_NODES 10000
#define E_EDGES 160000
#define ETOT    170000   // E + N self loops
#define H_HEADS 8
#define C_CH    128
#define D_DIM   1024
#define NBLK    3
#define NGRAPH  64
#define NEG_SLOPE 0.2f
#define BN_EPS  1e-5f

typedef __attribute__((ext_vector_type(8))) _Float16 half8;
typedef __attribute__((ext_vector_type(4))) _Float16 half4;
typedef __attribute__((ext_vector_type(2))) _Float16 half2v;
typedef __attribute__((ext_vector_type(4))) float f32x4;

// first index i in sorted batch[0..N) with batch[i] >= g
__device__ inline int lower_bound_batch(const int* __restrict__ batch, int g) {
    int lo = 0, hi = N_NODES;
    while (lo < hi) {
        int mid = (lo + hi) >> 1;
        if (batch[mid] < g) lo = mid + 1;
        else hi = mid;
    }
    return lo;
}

// ---------------- CSR build ----------------
__global__ void deg_kernel(const int* __restrict__ ei, int* __restrict__ deg) {
    int tid = blockIdx.x * blockDim.x + threadIdx.x;
    if (tid >= ETOT) return;
    int dst = (tid < E_EDGES) ? ei[E_EDGES + tid] : (tid - E_EDGES);
    atomicAdd(&deg[dst], 1);
}

__global__ void scan_kernel(const int* __restrict__ deg, int* __restrict__ ioff) {
    __shared__ int part[256];
    int t = threadIdx.x;
    const int CH = (N_NODES + 255) / 256; // 40
    int base = t * CH;
    int s = 0;
    for (int j = 0; j < CH; ++j) {
        int idx = base + j;
        if (idx < N_NODES) s += deg[idx];
    }
    part[t] = s;
    __syncthreads();
    for (int o = 1; o < 256; o <<= 1) {
        int v = 0;
        if (t >= o) v = part[t - o];
        __syncthreads();
        part[t] += v;
        __syncthreads();
    }
    int run = (t == 0) ? 0 : part[t - 1];
    for (int j = 0; j < CH; ++j) {
        int idx = base + j;
        if (idx < N_NODES) { ioff[idx] = run; run += deg[idx]; }
    }
}

__global__ void scatter_kernel(const int* __restrict__ ei, int* __restrict__ ioff,
                               int* __restrict__ csr_src) {
    int tid = blockIdx.x * blockDim.x + threadIdx.x;
    if (tid >= ETOT) return;
    int src, dst;
    if (tid < E_EDGES) { src = ei[tid]; dst = ei[E_EDGES + tid]; }
    else { src = dst = tid - E_EDGES; }
    int pos = atomicAdd(&ioff[dst], 1);
    csr_src[pos] = src;
}

// ---------------- x -> fp16 ----------------
__global__ __launch_bounds__(256) void xconv_kernel(const float* __restrict__ in,
                                                    _Float16* __restrict__ o, int n4) {
    int i = blockIdx.x * blockDim.x + threadIdx.x;
    if (i >= n4) return;
    float4 v = ((const float4*)in)[i];
    half4 h = {(_Float16)v.x, (_Float16)v.y, (_Float16)v.z, (_Float16)v.w};
    ((half4*)o)[i] = h;
}

// W [k][n] fp32 -> Wt [n][k] fp16 (transposed); blockIdx.z = layer
__global__ __launch_bounds__(256) void wtconv_kernel(const float* __restrict__ Wall,
                                                     _Float16* __restrict__ t16all) {
    const float* W = Wall + (size_t)blockIdx.z * D_DIM * D_DIM;
    _Float16* t16 = t16all + (size_t)blockIdx.z * D_DIM * D_DIM;
    __shared__ float t[32][33];
    int bn = blockIdx.x * 32;
    int bk = blockIdx.y * 32;
    int tx = threadIdx.x & 31;
    int ty = threadIdx.x >> 5;
#pragma unroll
    for (int r = 0; r < 32; r += 8)
        t[ty + r][tx] = W[(size_t)(bk + ty + r) * D_DIM + bn + tx];
    __syncthreads();
#pragma unroll
    for (int r = 0; r < 32; r += 8)
        t16[(size_t)(bn + ty + r) * D_DIM + bk + tx] = (_Float16)t[tx][ty + r];
}

// ---------------- fp16 MFMA GEMM + fused attention-logit epilogue ----------------
// R8 tile config (128x128, 4 waves) with XCD-flipped block mapping: 1D grid 640,
// c = bx&7 (= XCD under %8 round-robin), head = (bx>>3)&7, mt = c + 8*(bx>>6).
// Each XCD owns m-tiles {c, c+8, ...}: one hot 256 KB A-tile (reused by 8
// consecutive head-blocks) + 2 MB B per XCD -> L2-resident.
// Hout layout: head-major [8][N][128]. Block 0 zeroes bn-stats (consumed only
// by bn_stats/bn_apply later in the stream).
__global__ __launch_bounds__(256) void gemm_mfma_kernel(const _Float16* __restrict__ A,
                                                        const _Float16* __restrict__ Bt,
                                                        _Float16* __restrict__ Hout,
                                                        const float* __restrict__ att_s,
                                                        const float* __restrict__ att_d,
                                                        float* __restrict__ asrc,
                                                        float* __restrict__ adst,
                                                        float* __restrict__ stats, int M) {
    __shared__ short As[128 * 32]; // [m][k] fp16 bits
    __shared__ short Bs[128 * 32]; // [n][k]
    __shared__ float sA[128], sD[128];
    int bx = blockIdx.x;
    int tid = threadIdx.x;
    if (bx == 0) {
#pragma unroll
        for (int j = 0; j < 8; ++j) stats[tid + j * 256] = 0.f;
    }
    int c = bx & 7;
    int head = (bx >> 3) & 7;
    int mt = c + 8 * (bx >> 6);
    if (mt >= 79) return;
    int bm = mt * 128;
    int bn = head * 128;
    int wave = tid >> 6;
    int lane = tid & 63;
    int wm = (wave >> 1) * 64;
    int wn = (wave & 1) * 64;
    int quad = lane >> 4;
    int l16 = lane & 15;

    f32x4 acc[4][4];
#pragma unroll
    for (int i = 0; i < 4; ++i)
#pragma unroll
        for (int j = 0; j < 4; ++j) acc[i][j] = (f32x4){0.f, 0.f, 0.f, 0.f};

    int srow = lane >> 2;
    int scol = (lane & 3) * 16;

    for (int kb = 0; kb < 32; ++kb) {
        int k0 = kb * 32;
#pragma unroll
        for (int r = 0; r < 2; ++r) {
            int arow = wave * 16 + r * 64 + srow;
            int grow = bm + arow;
            if (grow > M - 1) grow = M - 1;
            const char* gp = (const char*)(A + (size_t)grow * 1024 + k0) + scol;
            __builtin_amdgcn_global_load_lds(
                (const __attribute__((address_space(1))) void*)gp,
                (__attribute__((address_space(3))) void*)((char*)As + (wave * 16 + r * 64) * 64),
                16, 0, 0);
        }
#pragma unroll
        for (int r = 0; r < 2; ++r) {
            int brow = wave * 16 + r * 64 + srow;
            const char* gp = (const char*)(Bt + (size_t)(bn + brow) * 1024 + k0) + scol;
            __builtin_amdgcn_global_load_lds(
                (const __attribute__((address_space(1))) void*)gp,
                (__attribute__((address_space(3))) void*)((char*)Bs + (wave * 16 + r * 64) * 64),
                16, 0, 0);
        }
        __syncthreads();

        half8 af[4], bfr[4];
#pragma unroll
        for (int i = 0; i < 4; ++i)
            af[i] = *(const half8*)(As + (wm + i * 16 + l16) * 32 + quad * 8);
#pragma unroll
        for (int j = 0; j < 4; ++j)
            bfr[j] = *(const half8*)(Bs + (wn + j * 16 + l16) * 32 + quad * 8);
#pragma unroll
        for (int i = 0; i < 4; ++i)
#pragma unroll
            for (int j = 0; j < 4; ++j)
                acc[i][j] = __builtin_amdgcn_mfma_f32_16x16x32_f16(af[i], bfr[j], acc[i][j], 0, 0, 0);
        __syncthreads();
    }

    // attention-logit partial dots over this wave's 64 cols
    float wsv[4], wdv[4];
#pragma unroll
    for (int j = 0; j < 4; ++j) {
        int cc = wn + j * 16 + l16;
        wsv[j] = att_s[head * 128 + cc];
        wdv[j] = att_d[head * 128 + cc];
    }
    float psv[4][4], pdv[4][4];
#pragma unroll
    for (int i = 0; i < 4; ++i) {
#pragma unroll
        for (int reg = 0; reg < 4; ++reg) {
            float p = acc[i][0][reg] * wsv[0] + acc[i][1][reg] * wsv[1] +
                      acc[i][2][reg] * wsv[2] + acc[i][3][reg] * wsv[3];
            float q = acc[i][0][reg] * wdv[0] + acc[i][1][reg] * wdv[1] +
                      acc[i][2][reg] * wdv[2] + acc[i][3][reg] * wdv[3];
#pragma unroll
            for (int o = 1; o < 16; o <<= 1) {
                p += __shfl_xor(p, o);
                q += __shfl_xor(q, o);
            }
            psv[i][reg] = p;
            pdv[i][reg] = q;
        }
    }
    if ((wave & 1) == 0 && l16 == 0) {
#pragma unroll
        for (int i = 0; i < 4; ++i)
#pragma unroll
            for (int reg = 0; reg < 4; ++reg) {
                int r = wm + i * 16 + quad * 4 + reg;
                sA[r] = psv[i][reg];
                sD[r] = pdv[i][reg];
            }
    }
    // store h fp16, head-major: Hout[head][row][col128]
#pragma unroll
    for (int i = 0; i < 4; ++i) {
#pragma unroll
        for (int reg = 0; reg < 4; ++reg) {
            int gr = bm + wm + i * 16 + quad * 4 + reg;
            if (gr < M) {
                _Float16* hp = Hout + (size_t)head * N_NODES * 128 + (size_t)gr * 128 + wn + l16;
#pragma unroll
                for (int j = 0; j < 4; ++j) hp[j * 16] = (_Float16)acc[i][j][reg];
            }
        }
    }
    __syncthreads();
    if ((wave & 1) == 1 && l16 == 0) {
#pragma unroll
        for (int i = 0; i < 4; ++i)
#pragma unroll
            for (int reg = 0; reg < 4; ++reg) {
                int r = wm + i * 16 + quad * 4 + reg;
                int gr = bm + r;
                if (gr < M) {
                    asrc[gr * 8 + head] = sA[r] + psv[i][reg];
                    adst[gr * 8 + head] = sD[r] + pdv[i][reg];
                }
            }
    }
}

// ---------------- fused edge-softmax aggregation, head-partitioned ----------------
// head = bx&7 (XCD L2 affinity); h16 head-major [8][N][128]; edge loop x4
// unrolled. NO stats work here — R13's fused stats reduced only 2 rows before
// the global atomic (5000 serialized atomics/column, 160 MB extra writes,
// 8x slower agg). bn_stats' own pass reduces 5000 rows/atomic instead.
__global__ __launch_bounds__(256) void agg_kernel(const _Float16* __restrict__ h16,
                                                  const float* __restrict__ asrc,
                                                  const float* __restrict__ adst,
                                                  const int* __restrict__ ioff,
                                                  const int* __restrict__ csr_src,
                                                  const _Float16* __restrict__ prevh,
                                                  const float* __restrict__ bias,
                                                  _Float16* __restrict__ yout) {
    int bx = blockIdx.x;
    int tid = threadIdx.x;
    int head = bx & 7;
    int chunk = bx >> 3;
    int sub = tid >> 5;
    int lane = tid & 31;
    int n = chunk * 8 + sub;          // N=10000 divisible by 8
    int c4 = lane * 4;
    const _Float16* hh = h16 + (size_t)head * N_NODES * 128;
    int start = (n == 0) ? 0 : ioff[n - 1];
    int end = ioff[n];
    float ad = adst[n * 8 + head];
    float den = 0.f;
    float4 acc = make_float4(0.f, 0.f, 0.f, 0.f);
    int p = start;
    for (; p + 4 <= end; p += 4) {
        int s0 = csr_src[p + 0];
        int s1 = csr_src[p + 1];
        int s2 = csr_src[p + 2];
        int s3 = csr_src[p + 3];
        float a0 = asrc[s0 * 8 + head];
        float a1 = asrc[s1 * 8 + head];
        float a2 = asrc[s2 * 8 + head];
        float a3 = asrc[s3 * 8 + head];
        half4 h0 = *(const half4*)(hh + (size_t)s0 * 128 + c4);
        half4 h1 = *(const half4*)(hh + (size_t)s1 * 128 + c4);
        half4 h2 = *(const half4*)(hh + (size_t)s2 * 128 + c4);
        half4 h3 = *(const half4*)(hh + (size_t)s3 * 128 + c4);
        float e0 = a0 + ad; e0 = (e0 > 0.f) ? e0 : NEG_SLOPE * e0;
        float e1 = a1 + ad; e1 = (e1 > 0.f) ? e1 : NEG_SLOPE * e1;
        float e2 = a2 + ad; e2 = (e2 > 0.f) ? e2 : NEG_SLOPE * e2;
        float e3 = a3 + ad; e3 = (e3 > 0.f) ? e3 : NEG_SLOPE * e3;
        float x0 = __expf(e0), x1 = __expf(e1), x2 = __expf(e2), x3 = __expf(e3);
        den += (x0 + x1) + (x2 + x3);
        acc.x += x0 * (float)h0[0] + x1 * (float)h1[0] + x2 * (float)h2[0] + x3 * (float)h3[0];
        acc.y += x0 * (float)h0[1] + x1 * (float)h1[1] + x2 * (float)h2[1] + x3 * (float)h3[1];
        acc.z += x0 * (float)h0[2] + x1 * (float)h1[2] + x2 * (float)h2[2] + x3 * (float)h3[2];
        acc.w += x0 * (float)h0[3] + x1 * (float)h1[3] + x2 * (float)h2[3] + x3 * (float)h3[3];
    }
    for (; p < end; ++p) {
        int s = csr_src[p];
        float e = asrc[s * 8 + head] + ad;
        e = (e > 0.f) ? e : NEG_SLOPE * e;
        float ex = __expf(e);
        den += ex;
        half4 hv = *(const half4*)(hh + (size_t)s * 128 + c4);
        acc.x = fmaf(ex, (float)hv[0], acc.x);
        acc.y = fmaf(ex, (float)hv[1], acc.y);
        acc.z = fmaf(ex, (float)hv[2], acc.z);
        acc.w = fmaf(ex, (float)hv[3], acc.w);
    }
    float invd = 1.0f / den;
    int col = head * 128 + c4;
    half4 ph = *(const half4*)(prevh + (size_t)n * 1024 + col);
    float4 bv = *(const float4*)(bias + col);
    float r0 = fmaf(acc.x, invd, (float)ph[0] + bv.x);
    float r1 = fmaf(acc.y, invd, (float)ph[1] + bv.y);
    float r2 = fmaf(acc.z, invd, (float)ph[2] + bv.z);
    float r3 = fmaf(acc.w, invd, (float)ph[3] + bv.w);
    half4 o = {(_Float16)r0, (_Float16)r1, (_Float16)r2, (_Float16)r3};
    *(half4*)(yout + (size_t)n * 1024 + col) = o;
}

// ---------------- batchnorm (fp16 y) ----------------
// Stats from the same fp16-rounded y16 that bn_apply reads (R11 lesson), with
// 5000-row pre-reduction per atomic (R13 lesson). stats zeroed by gemm block 0.
__global__ void bn_stats_kernel(const _Float16* __restrict__ y, float* __restrict__ stats) {
    int col = (blockIdx.x * 256 + threadIdx.x) * 2;  // grid.x = 2
    float s0 = 0.f, s1 = 0.f, q0 = 0.f, q1 = 0.f;
    for (int r = blockIdx.y; r < N_NODES; r += gridDim.y) {
        half2v v = *(const half2v*)(y + (size_t)r * 1024 + col);
        float a = (float)v[0], b = (float)v[1];
        s0 += a; q0 += a * a;
        s1 += b; q1 += b * b;
    }
    atomicAdd(&stats[col], s0);
    atomicAdd(&stats[col + 1], s1);
    atomicAdd(&stats[1024 + col], q0);
    atomicAdd(&stats[1024 + col + 1], q1);
}

// normalize+relu: y16 -> o16 (o is next layer's GEMM A / prev / pool input)
__global__ void bn_apply_kernel(const _Float16* __restrict__ y, const float* __restrict__ stats,
                                const float* __restrict__ gamma, const float* __restrict__ beta,
                                _Float16* __restrict__ oout) {
    int idx4 = blockIdx.x * blockDim.x + threadIdx.x;
    if (idx4 >= N_NODES * D_DIM / 4) return;
    int base = idx4 * 4;
    int col = base & 1023;
    const float invN = 1.0f / (float)N_NODES;
    half4 v = ((const half4*)y)[idx4];
    float r[4];
#pragma unroll
    for (int j = 0; j < 4; ++j) {
        int cc = col + j;
        float mu = stats[cc] * invN;
        float var = stats[1024 + cc] * invN - mu * mu;
        float t = ((float)v[j] - mu) * rsqrtf(var + BN_EPS) * gamma[cc] + beta[cc];
        r[j] = fmaxf(t, 0.f);
    }
    half4 h = {(_Float16)r[0], (_Float16)r[1], (_Float16)r[2], (_Float16)r[3]};
    ((half4*)oout)[idx4] = h;
}

// ---------------- fused pooling + final linear (one dispatch) ----------------
__global__ __launch_bounds__(256) void poolfinal_kernel(const _Float16* __restrict__ h3,
                                                        const int* __restrict__ batch,
                                                        const float* __restrict__ Wout,
                                                        const float* __restrict__ bout,
                                                        float* __restrict__ out) {
    int g = blockIdx.x;
    int t = threadIdx.x;
    int col = t * 4;
    int lo = lower_bound_batch(batch, g);
    int hi = lower_bound_batch(batch, g + 1);
    float a0 = 0.f, a1 = 0.f, a2 = 0.f, a3 = 0.f;
    for (int r = lo; r < hi; ++r) {
        half4 v = *(const half4*)(h3 + (size_t)r * 1024 + col);
        a0 += (float)v[0]; a1 += (float)v[1]; a2 += (float)v[2]; a3 += (float)v[3];
    }
    float p0 = a0 * Wout[2 * col] + a1 * Wout[2 * (col + 1)] +
               a2 * Wout[2 * (col + 2)] + a3 * Wout[2 * (col + 3)];
    float p1 = a0 * Wout[2 * col + 1] + a1 * Wout[2 * (col + 1) + 1] +
               a2 * Wout[2 * (col + 2) + 1] + a3 * Wout[2 * (col + 3) + 1];
    __shared__ float s0[256], s1[256];
    s0[t] = p0; s1[t] = p1;
    __syncthreads();
    for (int o = 128; o; o >>= 1) {
        if (t < o) { s0[t] += s0[t + o]; s1[t] += s1[t + o]; }
        __syncthreads();
    }
    if (t == 0) {
        float inv = 1.0f / fmaxf((float)(hi - lo), 1.0f);
        out[g * 2 + 0] = s0[0] * inv + bout[0];
        out[g * 2 + 1] = s1[0] * inv + bout[1];
    }
}

extern "C" void kernel_launch(void* const* d_in, const int* in_sizes, int n_in,
                              void* d_out, int out_size, void* d_ws, size_t ws_size,
                              hipStream_t stream) {
    const float* x        = (const float*)d_in[0];
    const int*   ei       = (const int*)d_in[1];
    const int*   batch    = (const int*)d_in[2];
    const float* W        = (const float*)d_in[3];
    const float* att_src  = (const float*)d_in[4];
    const float* att_dst  = (const float*)d_in[5];
    const float* att_bias = (const float*)d_in[6];
    const float* gamma    = (const float*)d_in[7];
    const float* beta     = (const float*)d_in[8];
    const float* Wout     = (const float*)d_in[9];
    const float* bout     = (const float*)d_in[10];
    float* out = (float*)d_out;

    const size_t ND = (size_t)N_NODES * D_DIM;
    float* ws = (float*)d_ws;
    float* asrc   = ws;                                  // N*H
    float* adst   = asrc + (size_t)N_NODES * H_HEADS;    // N*H
    float* stats  = adst + (size_t)N_NODES * H_HEADS;    // 2*D
    int* ideg     = (int*)(stats + 2 * D_DIM);           // N
    int* ioff     = ideg + N_NODES;                      // N
    int* csr_src  = ioff + N_NODES;                      // ETOT
    _Float16* bufP  = (_Float16*)(csr_src + ETOT);       // N*D: x16 -> o1 -> o2
    _Float16* bufO0 = bufP + ND;                         // N*D: o0
    _Float16* h16   = bufO0 + ND;                        // N*D: GEMM out, [8][N][128]
    _Float16* y16   = h16 + ND;                          // N*D: agg out (pre-BN)
    _Float16* Wt3   = y16 + ND;                          // 3*D*D fp16 (W^T)
    // total ≈ 93 MB

    hipMemsetAsync(ideg, 0, N_NODES * sizeof(int), stream);
    deg_kernel<<<(ETOT + 255) / 256, 256, 0, stream>>>(ei, ideg);
    scan_kernel<<<1, 256, 0, stream>>>(ideg, ioff);
    scatter_kernel<<<(ETOT + 255) / 256, 256, 0, stream>>>(ei, ioff, csr_src);
    xconv_kernel<<<(int)(ND / 4 + 255) / 256, 256, 0, stream>>>(x, bufP, (int)(ND / 4));
    wtconv_kernel<<<dim3(32, 32, 3), 256, 0, stream>>>(W, Wt3);

    // layer i: A = Ain[i]; prev = Pin[i] (all fp16); bn output -> Oout[i]
    const _Float16* Ain[3]  = {bufP, bufO0, bufP};
    const _Float16* Pin[3]  = {bufP, bufP, bufO0};
    _Float16* Oout[3]       = {bufO0, bufP, bufP};

    for (int i = 0; i < NBLK; ++i) {
        gemm_mfma_kernel<<<640, 256, 0, stream>>>(
            Ain[i], Wt3 + (size_t)i * D_DIM * D_DIM, h16,
            att_src + i * H_HEADS * C_CH, att_dst + i * H_HEADS * C_CH,
            asrc, adst, stats, N_NODES);
        agg_kernel<<<N_NODES, 256, 0, stream>>>(h16, asrc, adst, ioff, csr_src,
                                                Pin[i], att_bias + i * D_DIM, y16);
        bn_stats_kernel<<<dim3(2, 128), 256, 0, stream>>>(y16, stats);
        bn_apply_kernel<<<(int)(ND / 4 + 255) / 256, 256, 0, stream>>>(
            y16, stats, gamma + i * D_DIM, beta + i * D_DIM, Oout[i]);
    }

    poolfinal_kernel<<<NGRAPH, 256, 0, stream>>>(bufP, batch, Wout, bout, out);
}

// Round 15
// 580.625 us; speedup vs baseline: 3.2020x; 1.0483x over previous
//
#include <hip/hip_runtime.h>
#include <hip/hip_bf16.h>

#define N_NODES 10000
#define E_EDGES 160000
#define ETOT    170000   // E + N self loops
#define H_HEADS 8
#define C_CH    128
#define D_DIM   1024
#define NBLK    3
#define NGRAPH  64
#define NEG_SLOPE 0.2f
#define BN_EPS  1e-5f

typedef __attribute__((ext_vector_type(8))) _Float16 half8;
typedef __attribute__((ext_vector_type(4))) _Float16 half4;
typedef __attribute__((ext_vector_type(2))) _Float16 half2v;
typedef __attribute__((ext_vector_type(4))) float f32x4;

// first index i in sorted batch[0..N) with batch[i] >= g
__device__ inline int lower_bound_batch(const int* __restrict__ batch, int g) {
    int lo = 0, hi = N_NODES;
    while (lo < hi) {
        int mid = (lo + hi) >> 1;
        if (batch[mid] < g) lo = mid + 1;
        else hi = mid;
    }
    return lo;
}

// ---------------- CSR build ----------------
__global__ void deg_kernel(const int* __restrict__ ei, int* __restrict__ deg) {
    int tid = blockIdx.x * blockDim.x + threadIdx.x;
    if (tid >= ETOT) return;
    int dst = (tid < E_EDGES) ? ei[E_EDGES + tid] : (tid - E_EDGES);
    atomicAdd(&deg[dst], 1);
}

__global__ void scan_kernel(const int* __restrict__ deg, int* __restrict__ ioff) {
    __shared__ int part[256];
    int t = threadIdx.x;
    const int CH = (N_NODES + 255) / 256; // 40
    int base = t * CH;
    int s = 0;
    for (int j = 0; j < CH; ++j) {
        int idx = base + j;
        if (idx < N_NODES) s += deg[idx];
    }
    part[t] = s;
    __syncthreads();
    for (int o = 1; o < 256; o <<= 1) {
        int v = 0;
        if (t >= o) v = part[t - o];
        __syncthreads();
        part[t] += v;
        __syncthreads();
    }
    int run = (t == 0) ? 0 : part[t - 1];
    for (int j = 0; j < CH; ++j) {
        int idx = base + j;
        if (idx < N_NODES) { ioff[idx] = run; run += deg[idx]; }
    }
}

__global__ void scatter_kernel(const int* __restrict__ ei, int* __restrict__ ioff,
                               int* __restrict__ csr_src) {
    int tid = blockIdx.x * blockDim.x + threadIdx.x;
    if (tid >= ETOT) return;
    int src, dst;
    if (tid < E_EDGES) { src = ei[tid]; dst = ei[E_EDGES + tid]; }
    else { src = dst = tid - E_EDGES; }
    int pos = atomicAdd(&ioff[dst], 1);
    csr_src[pos] = src;
}

// ---------------- x -> fp16 ----------------
__global__ __launch_bounds__(256) void xconv_kernel(const float* __restrict__ in,
                                                    _Float16* __restrict__ o, int n4) {
    int i = blockIdx.x * blockDim.x + threadIdx.x;
    if (i >= n4) return;
    float4 v = ((const float4*)in)[i];
    half4 h = {(_Float16)v.x, (_Float16)v.y, (_Float16)v.z, (_Float16)v.w};
    ((half4*)o)[i] = h;
}

// W [k][n] fp32 -> Wt [n][k] fp16 (transposed); blockIdx.z = layer
__global__ __launch_bounds__(256) void wtconv_kernel(const float* __restrict__ Wall,
                                                     _Float16* __restrict__ t16all) {
    const float* W = Wall + (size_t)blockIdx.z * D_DIM * D_DIM;
    _Float16* t16 = t16all + (size_t)blockIdx.z * D_DIM * D_DIM;
    __shared__ float t[32][33];
    int bn = blockIdx.x * 32;
    int bk = blockIdx.y * 32;
    int tx = threadIdx.x & 31;
    int ty = threadIdx.x >> 5;
#pragma unroll
    for (int r = 0; r < 32; r += 8)
        t[ty + r][tx] = W[(size_t)(bk + ty + r) * D_DIM + bn + tx];
    __syncthreads();
#pragma unroll
    for (int r = 0; r < 32; r += 8)
        t16[(size_t)(bn + ty + r) * D_DIM + bk + tx] = (_Float16)t[tx][ty + r];
}

// ---------------- fp16 MFMA GEMM + fused attention-logit epilogue ----------------
// R8 tile config (128x128, 4 waves) with XCD-flipped block mapping: 1D grid 640,
// c = bx&7 (= XCD under %8 round-robin), head = (bx>>3)&7, mt = c + 8*(bx>>6).
// Each XCD owns m-tiles {c, c+8, ...}: one hot 256 KB A-tile (reused by 8
// consecutive head-blocks) + 2 MB B per XCD -> L2-resident. (R14: gemm dropped
// out of the top-5, i.e. <58.8 us — the mapping works.)
// Hout layout: head-major [8][N][128]. Block 0 zeroes bn-stats.
__global__ __launch_bounds__(256) void gemm_mfma_kernel(const _Float16* __restrict__ A,
                                                        const _Float16* __restrict__ Bt,
                                                        _Float16* __restrict__ Hout,
                                                        const float* __restrict__ att_s,
                                                        const float* __restrict__ att_d,
                                                        float* __restrict__ asrc,
                                                        float* __restrict__ adst,
                                                        float* __restrict__ stats, int M) {
    __shared__ short As[128 * 32]; // [m][k] fp16 bits
    __shared__ short Bs[128 * 32]; // [n][k]
    __shared__ float sA[128], sD[128];
    int bx = blockIdx.x;
    int tid = threadIdx.x;
    if (bx == 0) {
#pragma unroll
        for (int j = 0; j < 8; ++j) stats[tid + j * 256] = 0.f;
    }
    int c = bx & 7;
    int head = (bx >> 3) & 7;
    int mt = c + 8 * (bx >> 6);
    if (mt >= 79) return;
    int bm = mt * 128;
    int bn = head * 128;
    int wave = tid >> 6;
    int lane = tid & 63;
    int wm = (wave >> 1) * 64;
    int wn = (wave & 1) * 64;
    int quad = lane >> 4;
    int l16 = lane & 15;

    f32x4 acc[4][4];
#pragma unroll
    for (int i = 0; i < 4; ++i)
#pragma unroll
        for (int j = 0; j < 4; ++j) acc[i][j] = (f32x4){0.f, 0.f, 0.f, 0.f};

    int srow = lane >> 2;
    int scol = (lane & 3) * 16;

    for (int kb = 0; kb < 32; ++kb) {
        int k0 = kb * 32;
#pragma unroll
        for (int r = 0; r < 2; ++r) {
            int arow = wave * 16 + r * 64 + srow;
            int grow = bm + arow;
            if (grow > M - 1) grow = M - 1;
            const char* gp = (const char*)(A + (size_t)grow * 1024 + k0) + scol;
            __builtin_amdgcn_global_load_lds(
                (const __attribute__((address_space(1))) void*)gp,
                (__attribute__((address_space(3))) void*)((char*)As + (wave * 16 + r * 64) * 64),
                16, 0, 0);
        }
#pragma unroll
        for (int r = 0; r < 2; ++r) {
            int brow = wave * 16 + r * 64 + srow;
            const char* gp = (const char*)(Bt + (size_t)(bn + brow) * 1024 + k0) + scol;
            __builtin_amdgcn_global_load_lds(
                (const __attribute__((address_space(1))) void*)gp,
                (__attribute__((address_space(3))) void*)((char*)Bs + (wave * 16 + r * 64) * 64),
                16, 0, 0);
        }
        __syncthreads();

        half8 af[4], bfr[4];
#pragma unroll
        for (int i = 0; i < 4; ++i)
            af[i] = *(const half8*)(As + (wm + i * 16 + l16) * 32 + quad * 8);
#pragma unroll
        for (int j = 0; j < 4; ++j)
            bfr[j] = *(const half8*)(Bs + (wn + j * 16 + l16) * 32 + quad * 8);
#pragma unroll
        for (int i = 0; i < 4; ++i)
#pragma unroll
            for (int j = 0; j < 4; ++j)
                acc[i][j] = __builtin_amdgcn_mfma_f32_16x16x32_f16(af[i], bfr[j], acc[i][j], 0, 0, 0);
        __syncthreads();
    }

    // attention-logit partial dots over this wave's 64 cols
    float wsv[4], wdv[4];
#pragma unroll
    for (int j = 0; j < 4; ++j) {
        int cc = wn + j * 16 + l16;
        wsv[j] = att_s[head * 128 + cc];
        wdv[j] = att_d[head * 128 + cc];
    }
    float psv[4][4], pdv[4][4];
#pragma unroll
    for (int i = 0; i < 4; ++i) {
#pragma unroll
        for (int reg = 0; reg < 4; ++reg) {
            float p = acc[i][0][reg] * wsv[0] + acc[i][1][reg] * wsv[1] +
                      acc[i][2][reg] * wsv[2] + acc[i][3][reg] * wsv[3];
            float q = acc[i][0][reg] * wdv[0] + acc[i][1][reg] * wdv[1] +
                      acc[i][2][reg] * wdv[2] + acc[i][3][reg] * wdv[3];
#pragma unroll
            for (int o = 1; o < 16; o <<= 1) {
                p += __shfl_xor(p, o);
                q += __shfl_xor(q, o);
            }
            psv[i][reg] = p;
            pdv[i][reg] = q;
        }
    }
    if ((wave & 1) == 0 && l16 == 0) {
#pragma unroll
        for (int i = 0; i < 4; ++i)
#pragma unroll
            for (int reg = 0; reg < 4; ++reg) {
                int r = wm + i * 16 + quad * 4 + reg;
                sA[r] = psv[i][reg];
                sD[r] = pdv[i][reg];
            }
    }
    // store h fp16, head-major: Hout[head][row][col128]
#pragma unroll
    for (int i = 0; i < 4; ++i) {
#pragma unroll
        for (int reg = 0; reg < 4; ++reg) {
            int gr = bm + wm + i * 16 + quad * 4 + reg;
            if (gr < M) {
                _Float16* hp = Hout + (size_t)head * N_NODES * 128 + (size_t)gr * 128 + wn + l16;
#pragma unroll
                for (int j = 0; j < 4; ++j) hp[j * 16] = (_Float16)acc[i][j][reg];
            }
        }
    }
    __syncthreads();
    if ((wave & 1) == 1 && l16 == 0) {
#pragma unroll
        for (int i = 0; i < 4; ++i)
#pragma unroll
            for (int reg = 0; reg < 4; ++reg) {
                int r = wm + i * 16 + quad * 4 + reg;
                int gr = bm + r;
                if (gr < M) {
                    asrc[gr * 8 + head] = sA[r] + psv[i][reg];
                    adst[gr * 8 + head] = sD[r] + pdv[i][reg];
                }
            }
    }
}

// ---------------- fused edge-softmax aggregation, head-partitioned ----------------
// head = bx&7 (XCD L2 affinity); h16 head-major [8][N][128]; edge loop x4
// unrolled. No stats work (R13 lesson: fusing stats destroyed the 5000-row
// pre-reduction -> 8x slower agg).
__global__ __launch_bounds__(256) void agg_kernel(const _Float16* __restrict__ h16,
                                                  const float* __restrict__ asrc,
                                                  const float* __restrict__ adst,
                                                  const int* __restrict__ ioff,
                                                  const int* __restrict__ csr_src,
                                                  const _Float16* __restrict__ prevh,
                                                  const float* __restrict__ bias,
                                                  _Float16* __restrict__ yout) {
    int bx = blockIdx.x;
    int tid = threadIdx.x;
    int head = bx & 7;
    int chunk = bx >> 3;
    int sub = tid >> 5;
    int lane = tid & 31;
    int n = chunk * 8 + sub;          // N=10000 divisible by 8
    int c4 = lane * 4;
    const _Float16* hh = h16 + (size_t)head * N_NODES * 128;
    int start = (n == 0) ? 0 : ioff[n - 1];
    int end = ioff[n];
    float ad = adst[n * 8 + head];
    float den = 0.f;
    float4 acc = make_float4(0.f, 0.f, 0.f, 0.f);
    int p = start;
    for (; p + 4 <= end; p += 4) {
        int s0 = csr_src[p + 0];
        int s1 = csr_src[p + 1];
        int s2 = csr_src[p + 2];
        int s3 = csr_src[p + 3];
        float a0 = asrc[s0 * 8 + head];
        float a1 = asrc[s1 * 8 + head];
        float a2 = asrc[s2 * 8 + head];
        float a3 = asrc[s3 * 8 + head];
        half4 h0 = *(const half4*)(hh + (size_t)s0 * 128 + c4);
        half4 h1 = *(const half4*)(hh + (size_t)s1 * 128 + c4);
        half4 h2 = *(const half4*)(hh + (size_t)s2 * 128 + c4);
        half4 h3 = *(const half4*)(hh + (size_t)s3 * 128 + c4);
        float e0 = a0 + ad; e0 = (e0 > 0.f) ? e0 : NEG_SLOPE * e0;
        float e1 = a1 + ad; e1 = (e1 > 0.f) ? e1 : NEG_SLOPE * e1;
        float e2 = a2 + ad; e2 = (e2 > 0.f) ? e2 : NEG_SLOPE * e2;
        float e3 = a3 + ad; e3 = (e3 > 0.f) ? e3 : NEG_SLOPE * e3;
        float x0 = __expf(e0), x1 = __expf(e1), x2 = __expf(e2), x3 = __expf(e3);
        den += (x0 + x1) + (x2 + x3);
        acc.x += x0 * (float)h0[0] + x1 * (float)h1[0] + x2 * (float)h2[0] + x3 * (float)h3[0];
        acc.y += x0 * (float)h0[1] + x1 * (float)h1[1] + x2 * (float)h2[1] + x3 * (float)h3[1];
        acc.z += x0 * (float)h0[2] + x1 * (float)h1[2] + x2 * (float)h2[2] + x3 * (float)h3[2];
        acc.w += x0 * (float)h0[3] + x1 * (float)h1[3] + x2 * (float)h2[3] + x3 * (float)h3[3];
    }
    for (; p < end; ++p) {
        int s = csr_src[p];
        float e = asrc[s * 8 + head] + ad;
        e = (e > 0.f) ? e : NEG_SLOPE * e;
        float ex = __expf(e);
        den += ex;
        half4 hv = *(const half4*)(hh + (size_t)s * 128 + c4);
        acc.x = fmaf(ex, (float)hv[0], acc.x);
        acc.y = fmaf(ex, (float)hv[1], acc.y);
        acc.z = fmaf(ex, (float)hv[2], acc.z);
        acc.w = fmaf(ex, (float)hv[3], acc.w);
    }
    float invd = 1.0f / den;
    int col = head * 128 + c4;
    half4 ph = *(const half4*)(prevh + (size_t)n * 1024 + col);
    float4 bv = *(const float4*)(bias + col);
    float r0 = fmaf(acc.x, invd, (float)ph[0] + bv.x);
    float r1 = fmaf(acc.y, invd, (float)ph[1] + bv.y);
    float r2 = fmaf(acc.z, invd, (float)ph[2] + bv.z);
    float r3 = fmaf(acc.w, invd, (float)ph[3] + bv.w);
    half4 o = {(_Float16)r0, (_Float16)r1, (_Float16)r2, (_Float16)r3};
    *(half4*)(yout + (size_t)n * 1024 + col) = o;
}

// ---------------- batchnorm (fp16 y) ----------------
// Stats from the same fp16-rounded y16 that bn_apply reads (R11 lesson), with
// 5000-row pre-reduction per atomic (R13 lesson). stats zeroed by gemm block 0.
__global__ void bn_stats_kernel(const _Float16* __restrict__ y, float* __restrict__ stats) {
    int col = (blockIdx.x * 256 + threadIdx.x) * 2;  // grid.x = 2
    float s0 = 0.f, s1 = 0.f, q0 = 0.f, q1 = 0.f;
    for (int r = blockIdx.y; r < N_NODES; r += gridDim.y) {
        half2v v = *(const half2v*)(y + (size_t)r * 1024 + col);
        float a = (float)v[0], b = (float)v[1];
        s0 += a; q0 += a * a;
        s1 += b; q1 += b * b;
    }
    atomicAdd(&stats[col], s0);
    atomicAdd(&stats[col + 1], s1);
    atomicAdd(&stats[1024 + col], q0);
    atomicAdd(&stats[1024 + col + 1], q1);
}

// normalize+relu: y16 -> o16 (o is next layer's GEMM A / prev / pool input)
__global__ void bn_apply_kernel(const _Float16* __restrict__ y, const float* __restrict__ stats,
                                const float* __restrict__ gamma, const float* __restrict__ beta,
                                _Float16* __restrict__ oout) {
    int idx4 = blockIdx.x * blockDim.x + threadIdx.x;
    if (idx4 >= N_NODES * D_DIM / 4) return;
    int base = idx4 * 4;
    int col = base & 1023;
    const float invN = 1.0f / (float)N_NODES;
    half4 v = ((const half4*)y)[idx4];
    float r[4];
#pragma unroll
    for (int j = 0; j < 4; ++j) {
        int cc = col + j;
        float mu = stats[cc] * invN;
        float var = stats[1024 + cc] * invN - mu * mu;
        float t = ((float)v[j] - mu) * rsqrtf(var + BN_EPS) * gamma[cc] + beta[cc];
        r[j] = fmaxf(t, 0.f);
    }
    half4 h = {(_Float16)r[0], (_Float16)r[1], (_Float16)r[2], (_Float16)r[3]};
    ((half4*)oout)[idx4] = h;
}

// ---------------- pooling stage 1: partial col-sums, 512 blocks ----------------
// grid (8 row-chunks, 64 graphs); atomicAdd fp32 partials into pooled[g][col]
// (8 atomics/address). R14's fused 64-block poolfinal was 2%-occupancy latency-
// bound at 59 us — parallelism over rows restores it.
__global__ __launch_bounds__(256) void pool_kernel(const _Float16* __restrict__ h3,
                                                   const int* __restrict__ batch,
                                                   float* __restrict__ pooled) {
    int g = blockIdx.y;
    int col = threadIdx.x * 4;
    int lo = lower_bound_batch(batch, g);
    int hi = lower_bound_batch(batch, g + 1);
    int len = hi - lo;
    int r0 = lo + (int)(((long long)len * blockIdx.x) >> 3);
    int r1 = lo + (int)(((long long)len * (blockIdx.x + 1)) >> 3);
    float a0 = 0.f, a1 = 0.f, a2 = 0.f, a3 = 0.f;
    for (int r = r0; r < r1; ++r) {
        half4 v = *(const half4*)(h3 + (size_t)r * 1024 + col);
        a0 += (float)v[0]; a1 += (float)v[1]; a2 += (float)v[2]; a3 += (float)v[3];
    }
    if (r1 > r0) {
        atomicAdd(&pooled[(size_t)g * 1024 + col + 0], a0);
        atomicAdd(&pooled[(size_t)g * 1024 + col + 1], a1);
        atomicAdd(&pooled[(size_t)g * 1024 + col + 2], a2);
        atomicAdd(&pooled[(size_t)g * 1024 + col + 3], a3);
    }
}

__global__ void final_kernel(const float* __restrict__ pooled, const int* __restrict__ batch,
                             const float* __restrict__ Wout, const float* __restrict__ bout,
                             float* __restrict__ out) {
    int g = blockIdx.x;
    int t = threadIdx.x;
    float p0 = 0.f, p1 = 0.f;
    for (int d = t; d < 1024; d += 256) {
        float v = pooled[(size_t)g * 1024 + d];
        p0 = fmaf(v, Wout[2 * d], p0);
        p1 = fmaf(v, Wout[2 * d + 1], p1);
    }
    __shared__ float s0[256], s1[256];
    s0[t] = p0; s1[t] = p1;
    __syncthreads();
    for (int o = 128; o; o >>= 1) {
        if (t < o) { s0[t] += s0[t + o]; s1[t] += s1[t + o]; }
        __syncthreads();
    }
    if (t == 0) {
        int cnt = lower_bound_batch(batch, g + 1) - lower_bound_batch(batch, g);
        float inv = 1.0f / fmaxf((float)cnt, 1.0f);
        out[g * 2 + 0] = s0[0] * inv + bout[0];
        out[g * 2 + 1] = s1[0] * inv + bout[1];
    }
}

extern "C" void kernel_launch(void* const* d_in, const int* in_sizes, int n_in,
                              void* d_out, int out_size, void* d_ws, size_t ws_size,
                              hipStream_t stream) {
    const float* x        = (const float*)d_in[0];
    const int*   ei       = (const int*)d_in[1];
    const int*   batch    = (const int*)d_in[2];
    const float* W        = (const float*)d_in[3];
    const float* att_src  = (const float*)d_in[4];
    const float* att_dst  = (const float*)d_in[5];
    const float* att_bias = (const float*)d_in[6];
    const float* gamma    = (const float*)d_in[7];
    const float* beta     = (const float*)d_in[8];
    const float* Wout     = (const float*)d_in[9];
    const float* bout     = (const float*)d_in[10];
    float* out = (float*)d_out;

    const size_t ND = (size_t)N_NODES * D_DIM;
    float* ws = (float*)d_ws;
    float* asrc   = ws;                                  // N*H
    float* adst   = asrc + (size_t)N_NODES * H_HEADS;    // N*H
    float* stats  = adst + (size_t)N_NODES * H_HEADS;    // 2*D
    float* pooled = stats + 2 * D_DIM;                   // NG*D
    int* ideg     = (int*)(pooled + (size_t)NGRAPH * D_DIM); // N
    int* ioff     = ideg + N_NODES;                      // N
    int* csr_src  = ioff + N_NODES;                      // ETOT
    _Float16* bufP  = (_Float16*)(csr_src + ETOT);       // N*D: x16 -> o1 -> o2
    _Float16* bufO0 = bufP + ND;                         // N*D: o0
    _Float16* h16   = bufO0 + ND;                        // N*D: GEMM out, [8][N][128]
    _Float16* y16   = h16 + ND;                          // N*D: agg out (pre-BN)
    _Float16* Wt3   = y16 + ND;                          // 3*D*D fp16 (W^T)
    // total ≈ 93 MB

    hipMemsetAsync(ideg, 0, N_NODES * sizeof(int), stream);
    hipMemsetAsync(pooled, 0, (size_t)NGRAPH * D_DIM * sizeof(float), stream);
    deg_kernel<<<(ETOT + 255) / 256, 256, 0, stream>>>(ei, ideg);
    scan_kernel<<<1, 256, 0, stream>>>(ideg, ioff);
    scatter_kernel<<<(ETOT + 255) / 256, 256, 0, stream>>>(ei, ioff, csr_src);
    xconv_kernel<<<(int)(ND / 4 + 255) / 256, 256, 0, stream>>>(x, bufP, (int)(ND / 4));
    wtconv_kernel<<<dim3(32, 32, 3), 256, 0, stream>>>(W, Wt3);

    // layer i: A = Ain[i]; prev = Pin[i] (all fp16); bn output -> Oout[i]
    const _Float16* Ain[3]  = {bufP, bufO0, bufP};
    const _Float16* Pin[3]  = {bufP, bufP, bufO0};
    _Float16* Oout[3]       = {bufO0, bufP, bufP};

    for (int i = 0; i < NBLK; ++i) {
        gemm_mfma_kernel<<<640, 256, 0, stream>>>(
            Ain[i], Wt3 + (size_t)i * D_DIM * D_DIM, h16,
            att_src + i * H_HEADS * C_CH, att_dst + i * H_HEADS * C_CH,
            asrc, adst, stats, N_NODES);
        agg_kernel<<<N_NODES, 256, 0, stream>>>(h16, asrc, adst, ioff, csr_src,
                                                Pin[i], att_bias + i * D_DIM, y16);
        bn_stats_kernel<<<dim3(2, 128), 256, 0, stream>>>(y16, stats);
        bn_apply_kernel<<<(int)(ND / 4 + 255) / 256, 256, 0, stream>>>(
            y16, stats, gamma + i * D_DIM, beta + i * D_DIM, Oout[i]);
    }

    pool_kernel<<<dim3(8, NGRAPH), 256, 0, stream>>>(bufP, batch, pooled);
    final_kernel<<<NGRAPH, 256, 0, stream>>>(pooled, batch, Wout, bout, out);
}